// Round 21
// baseline (2214.802 us; speedup 1.0000x reference)
//
#include <hip/hip_runtime.h>
#include <hip/hip_fp16.h>
#include <cmath>

#define RN 512
#define RT 1024
#define RB 64
#define SMEM_BYTES 86016   // tiny real use; pad forces exactly 1 block/CU

typedef _Float16 half2v __attribute__((ext_vector_type(2)));

__device__ __forceinline__ float fast_tanh(float x) {
    float e = __expf(2.0f * x);
    return 1.0f - 2.0f / (e + 1.0f);
}
__device__ __forceinline__ unsigned pack2(float a, float b) {   // RNE
    return (unsigned)__half_as_ushort(__float2half(a)) |
           ((unsigned)__half_as_ushort(__float2half(b)) << 16);
}
__device__ __forceinline__ float dot2(unsigned wa, unsigned tb, float acc) {
    half2v a = __builtin_bit_cast(half2v, wa);
    half2v b = __builtin_bit_cast(half2v, tb);
    return __builtin_amdgcn_fdot2(a, b, acc, false);
}
template <int CTRL>
__device__ __forceinline__ float dpp_add(float x) {
    int p = __builtin_amdgcn_update_dpp(0, __float_as_int(x), CTRL, 0xf, 0xf, true);
    return x + __int_as_float(p);
}
__device__ __forceinline__ float red16(float x) {
    x = dpp_add<0xB1>(x);   // quad_perm xor1
    x = dpp_add<0x4E>(x);   // quad_perm xor2
    x = dpp_add<0x141>(x);  // row_half_mirror
    x = dpp_add<0x140>(x);  // row_mirror
    return x;
}
#define D2Q(acc, wq, tq) \
    acc = dot2((wq).x, (tq).x, acc); acc = dot2((wq).y, (tq).y, acc); \
    acc = dot2((wq).z, (tq).z, acc); acc = dot2((wq).w, (tq).w, acc);

#define PIN4(v) asm volatile("" : "+v"((v).x), "+v"((v).y), "+v"((v).z), "+v"((v).w));

#define LOADB(bb) { \
    const int b_ = (part + (bb)) & 3; \
    w##bb##_0 = wsrc[(b_ * 4 + 0) * 512]; PIN4(w##bb##_0) \
    w##bb##_1 = wsrc[(b_ * 4 + 1) * 512]; PIN4(w##bb##_1) \
    w##bb##_2 = wsrc[(b_ * 4 + 2) * 512]; PIN4(w##bb##_2) \
    w##bb##_3 = wsrc[(b_ * 4 + 3) * 512]; PIN4(w##bb##_3) }

#define DOTB(bb, tv) \
    D2Q(acc0, w##bb##_0, tv) D2Q(acc1, w##bb##_1, tv) \
    D2Q(acc2, w##bb##_2, tv) D2Q(acc3, w##bb##_3, tv)

// R20 champion (1865us: register-resident W, same-XCD quads, phase A before
// relaxed tid0 poll, DPP reduce, signal hoist) + two chain cuts:
// (1) X[t+1] prefetch moved AFTER the drain+signal -- the old top-of-step
//     prefetch made the pre-signal vmcnt(0) wait on an HBM load (~900cy ON
//     THE SIGNAL PATH every step). Its latency now hides under the next
//     poll window (>=2000cy).
// (2) exchange via a t-indexed f16-RNE packed side-buffer exP (fresh
//     addresses, plain store/load -- the R19-proven channel class; ws>=202MB
//     established by R19's fast path actually running). Tail pre-signal
//     work shrinks to one uint2 store; phase B = ONE dwordx4 per band and
//     zero pkrtz. outH (fp32 output) is stored after the signal, off-path.
__global__ void __launch_bounds__(512, 1) rnn_step_kernel(
    const float* __restrict__ h0,
    const float* __restrict__ X,
    const uint4* __restrict__ Wpk,        // [4 part][4 band][4 i][512 tid]
    const unsigned* __restrict__ tanh0pk, // 256 u32: packed tanh(h0) pairs
    float* __restrict__ outH,
    unsigned* __restrict__ exP,           // [b][t][256 u32] packed th pairs
    unsigned* __restrict__ ctr,
    unsigned* __restrict__ xcdctr)
{
    extern __shared__ unsigned char smem[];
    unsigned* ownpk = (unsigned*)smem;               // 64 u32: own th pairs
    int*      bc    = (int*)(smem + 256);
    unsigned* lctr  = (unsigned*)(smem + 264);

    const int tid = threadIdx.x;
    if (tid == 0) {
        unsigned xcd;
        asm volatile("s_getreg_b32 %0, hwreg(HW_REG_XCC_ID)" : "=s"(xcd));
        xcd &= 7u;
        unsigned rank = __hip_atomic_fetch_add(&xcdctr[xcd], 1u,
                            __ATOMIC_RELAXED, __HIP_MEMORY_SCOPE_AGENT) & 31u;
        int slot = (int)(xcd * 32u + rank);   // 0..255
        bc[0] = slot >> 2;                    // batch 0..63
        bc[1] = slot & 3;                     // part  0..3
        *lctr = 0u;
    }
    __syncthreads();
    const int batch = bc[0], part = bc[1];

    // W fragment -> 16 named uint4 registers (rotated: w0_* = own band)
    uint4 w0_0, w0_1, w0_2, w0_3;
    uint4 w1_0, w1_1, w1_2, w1_3;
    uint4 w2_0, w2_1, w2_2, w2_3;
    uint4 w3_0, w3_1, w3_2, w3_3;
    {
        const uint4* wsrc = Wpk + part * 8192 + tid;
        LOADB(0) LOADB(1) LOADB(2) LOADB(3)
    }

    const int rg = tid >> 4;                  // 0..31 : 4-row group
    const int kc = tid & 15;                  // 0..15 : 8-k sub-chunk per band
    const int row0 = part * 128 + rg * 4;

    float4 h = {0, 0, 0, 0};
    float4 xv = {0, 0, 0, 0};
    if (kc == 0) {
        h = *reinterpret_cast<const float4*>(h0 + row0);
        float t0 = tanhf(h.x), t1 = tanhf(h.y), t2 = tanhf(h.z), t3 = tanhf(h.w);
        ownpk[2 * rg]     = pack2(t0, t1);
        ownpk[2 * rg + 1] = pack2(t2, t3);
        xv = *reinterpret_cast<const float4*>(&X[(size_t)batch * RT * RN + row0]);
    }

    unsigned* gctr = ctr + batch * 32;        // 128B line per quad
    __syncthreads();                          // ownpk staged

    #pragma unroll 1
    for (int t = 0; t < RT; ++t) {
        // ---- phase A: own band from registers + ownpk (no partner dep) ----
        float acc0 = 0.f, acc1 = 0.f, acc2 = 0.f, acc3 = 0.f;
        {
            uint4 th = *reinterpret_cast<const uint4*>(&ownpk[4 * kc]);
            DOTB(0, th)
        }

        // ---- wait for all 4 parts of step t-1 (tid0 poll + barrier bcast) ----
        if (tid == 0 && t > 0) {
            const unsigned tgt = 4u * (unsigned)t;
            while (__hip_atomic_load(gctr, __ATOMIC_RELAXED,
                                     __HIP_MEMORY_SCOPE_AGENT) < tgt)
                __builtin_amdgcn_s_sleep(1);
        }
        __syncthreads();

        // ---- phase B: 3 partner bands, ONE packed dwordx4 each, no pkrtz ----
        const unsigned* srcP = (t == 0) ? tanh0pk
            : (exP + ((size_t)batch * RT + (t - 1)) * 256);
        {
            const int b1 = (part + 1) & 3;
            uint4 tv = *reinterpret_cast<const uint4*>(srcP + b1 * 64 + 4 * kc);
            DOTB(1, tv)
        }
        {
            const int b2 = (part + 2) & 3;
            uint4 tv = *reinterpret_cast<const uint4*>(srcP + b2 * 64 + 4 * kc);
            DOTB(2, tv)
        }
        {
            const int b3 = (part + 3) & 3;
            uint4 tv = *reinterpret_cast<const uint4*>(srcP + b3 * 64 + 4 * kc);
            DOTB(3, tv)
        }

        // ---- 16-lane all-reduce in VALU (DPP) ----
        acc0 = red16(acc0); acc1 = red16(acc1);
        acc2 = red16(acc2); acc3 = red16(acc3);

        // ---- tail (pre-signal minimum): update, pack, ONE uint2 store ----
        float t0 = 0.f, t1 = 0.f, t2 = 0.f, t3 = 0.f;
        if (kc == 0) {
            h.x = 0.9f * h.x + 0.1f * (acc0 + xv.x);
            h.y = 0.9f * h.y + 0.1f * (acc1 + xv.y);
            h.z = 0.9f * h.z + 0.1f * (acc2 + xv.z);
            h.w = 0.9f * h.w + 0.1f * (acc3 + xv.w);
            t0 = fast_tanh(h.x); t1 = fast_tanh(h.y);
            t2 = fast_tanh(h.z); t3 = fast_tanh(h.w);
            const unsigned u0 = pack2(t0, t1), u1 = pack2(t2, t3);
            *reinterpret_cast<uint2*>(
                exP + ((size_t)batch * RT + t) * 256 + part * 64 + 2 * rg) =
                make_uint2(u0, u1);
            ownpk[2 * rg]     = u0;
            ownpk[2 * rg + 1] = u1;
        }

        // drain covers ONLY the 8B exchange store (X prefetch not yet issued)
        asm volatile("s_waitcnt vmcnt(0)" ::: "memory");
        if ((tid & 63) == 0) {
            unsigned a = __hip_atomic_fetch_add(lctr, 1u, __ATOMIC_RELAXED,
                                                __HIP_MEMORY_SCOPE_WORKGROUP);
            if ((a & 7u) == 7u)   // 8th wave: all exchange stores in XCD L2
                __hip_atomic_fetch_add(gctr, 1u, __ATOMIC_RELAXED,
                                       __HIP_MEMORY_SCOPE_AGENT);
        }

        // ---- off-path: fp32 output store + next-X prefetch (hide under poll) ----
        if (kc == 0) {
            *reinterpret_cast<float4*>(&outH[((size_t)batch * RT + t) * RN + row0]) =
                make_float4(t0, t1, t2, t3);
            const int tn = (t + 1 < RT) ? t + 1 : t;
            xv = *reinterpret_cast<const float4*>(&X[((size_t)batch * RT + tn) * RN + row0]);
        }
        __syncthreads();   // ownpk coherence for next step's phase A
    }
}

// one-time: W -> f16 pairs in exact per-read order
// Wpk[part*8192 + (b*4+i)*512 + tid] = W[part*128+(tid>>4)*4+i][b*128+(tid&15)*8 ..+8]
__global__ void pack_w(const float* __restrict__ W, uint4* __restrict__ Wpk)
{
    int o = blockIdx.x * blockDim.x + threadIdx.x;
    if (o >= 32768) return;
    int part = o >> 13;
    int b    = (o >> 11) & 3;
    int i    = (o >> 9) & 3;
    int tid  = o & 511;
    int row  = part * 128 + (tid >> 4) * 4 + i;
    int k0   = b * 128 + (tid & 15) * 8;
    const float* s = W + (size_t)row * RN + k0;
    uint4 v;
    v.x = pack2(s[0], s[1]); v.y = pack2(s[2], s[3]);
    v.z = pack2(s[4], s[5]); v.w = pack2(s[6], s[7]);
    Wpk[o] = v;
}

// geometry epilogue: geo[b,t,:] = hidden[b,t,:] @ Gw^T + Gb ; one wave per (b,t)
__global__ void geom_kernel(const float* __restrict__ hid,
                            const float* __restrict__ Gw,
                            const float* __restrict__ Gb,
                            float* __restrict__ geo)
{
    const int wid  = (blockIdx.x * blockDim.x + threadIdx.x) >> 6;
    const int lane = threadIdx.x & 63;
    if (wid >= RB * RT) return;
    const float* rowp = hid + (size_t)wid * RN;
    float g0 = 0.f, g1 = 0.f;
    #pragma unroll
    for (int j = 0; j < 8; ++j) {
        float v = rowp[lane + 64 * j];
        g0 = fmaf(v, Gw[lane + 64 * j], g0);
        g1 = fmaf(v, Gw[RN + lane + 64 * j], g1);
    }
    #pragma unroll
    for (int m = 32; m >= 1; m >>= 1) {
        g0 += __shfl_xor(g0, m);
        g1 += __shfl_xor(g1, m);
    }
    if (lane == 0) {
        geo[(size_t)wid * 2]     = g0 + Gb[0];
        geo[(size_t)wid * 2 + 1] = g1 + Gb[1];
    }
}

// per-launch init: packed tanh(h0) pairs + zero counters (ws poisoned once,
// never re-poisoned -> re-init every call; deterministic). exP needs no init:
// written-before-read every step by protocol (t-indexed, fresh addresses).
__global__ void init_misc(const float* __restrict__ h0,
                          unsigned* __restrict__ tanh0pk,
                          unsigned* __restrict__ ctr,
                          unsigned* __restrict__ xcdctr)
{
    int i = blockIdx.x * blockDim.x + threadIdx.x;
    if (i < 256) tanh0pk[i] = pack2(tanhf(h0[2 * i]), tanhf(h0[2 * i + 1]));
    if (i < RB * 32) ctr[i] = 0u;
    if (i < 8) xcdctr[i] = 0u;
}

extern "C" void kernel_launch(void* const* d_in, const int* in_sizes, int n_in,
                              void* d_out, int out_size, void* d_ws, size_t ws_size,
                              hipStream_t stream)
{
    const float* h0 = (const float*)d_in[0];
    const float* X  = (const float*)d_in[1];
    const float* W  = (const float*)d_in[2];
    const float* Gw = (const float*)d_in[3];
    const float* Gb = (const float*)d_in[4];

    float* outH = (float*)d_out;
    float* geo  = outH + (size_t)RB * RT * RN;

    unsigned* exP     = (unsigned*)d_ws;                   // 64*1024*256 u32 = 64 MB
    unsigned* tanh0pk = exP + (size_t)RB * RT * 256;       // 256 u32
    unsigned* ctr     = tanh0pk + 256;                     // 64*32 u32
    unsigned* xcdctr  = ctr + RB * 32;                     // 8 u32
    uint4*    Wpk     = (uint4*)(((uintptr_t)(xcdctr + 8) + 63) & ~(uintptr_t)63);

    (void)hipFuncSetAttribute((const void*)rnn_step_kernel,
                              hipFuncAttributeMaxDynamicSharedMemorySize, SMEM_BYTES);

    pack_w<<<64, 512, 0, stream>>>(W, Wpk);
    init_misc<<<8, 512, 0, stream>>>(h0, tanh0pk, ctr, xcdctr);

    void* kargs[] = { (void*)&h0, (void*)&X, (void*)&Wpk, (void*)&tanh0pk,
                      (void*)&outH, (void*)&exP, (void*)&ctr, (void*)&xcdctr };
    (void)hipLaunchCooperativeKernel(rnn_step_kernel, dim3(256), dim3(512),
                                     kargs, SMEM_BYTES, stream);

    geom_kernel<<<(RB * RT * 64 + 255) / 256, 256, 0, stream>>>(outH, Gw, Gb, geo);
}

// Round 22
// 1859.434 us; speedup vs baseline: 1.1911x; 1.1911x over previous
//
#include <hip/hip_runtime.h>
#include <hip/hip_fp16.h>
#include <cmath>

#define RN 512
#define RT 1024
#define RB 64
#define SMEM_BYTES 86016   // tiny real use; pad forces exactly 1 block/CU

typedef _Float16 half2v __attribute__((ext_vector_type(2)));

__device__ __forceinline__ float fast_tanh(float x) {
    float e = __expf(2.0f * x);
    return 1.0f - 2.0f / (e + 1.0f);
}
__device__ __forceinline__ unsigned pack2(float a, float b) {   // RNE
    return (unsigned)__half_as_ushort(__float2half(a)) |
           ((unsigned)__half_as_ushort(__float2half(b)) << 16);
}
__device__ __forceinline__ unsigned pkrtz(float a, float b) {
    auto h = __builtin_amdgcn_cvt_pkrtz(a, b);
    return __builtin_bit_cast(unsigned, h);
}
__device__ __forceinline__ float dot2(unsigned wa, unsigned tb, float acc) {
    half2v a = __builtin_bit_cast(half2v, wa);
    half2v b = __builtin_bit_cast(half2v, tb);
    return __builtin_amdgcn_fdot2(a, b, acc, false);
}
template <int CTRL>
__device__ __forceinline__ float dpp_add(float x) {
    int p = __builtin_amdgcn_update_dpp(0, __float_as_int(x), CTRL, 0xf, 0xf, true);
    return x + __int_as_float(p);
}
__device__ __forceinline__ float red16(float x) {
    x = dpp_add<0xB1>(x);   // quad_perm xor1
    x = dpp_add<0x4E>(x);   // quad_perm xor2
    x = dpp_add<0x141>(x);  // row_half_mirror
    x = dpp_add<0x140>(x);  // row_mirror
    return x;
}
#define D2Q(acc, wq, tq) \
    acc = dot2((wq).x, (tq).x, acc); acc = dot2((wq).y, (tq).y, acc); \
    acc = dot2((wq).z, (tq).z, acc); acc = dot2((wq).w, (tq).w, acc);

#define PIN4(v) asm volatile("" : "+v"((v).x), "+v"((v).y), "+v"((v).z), "+v"((v).w));

#define LOADB(bb) { \
    const int b_ = (part + (bb)) & 3; \
    w##bb##_0 = wsrc[(b_ * 4 + 0) * 512]; PIN4(w##bb##_0) \
    w##bb##_1 = wsrc[(b_ * 4 + 1) * 512]; PIN4(w##bb##_1) \
    w##bb##_2 = wsrc[(b_ * 4 + 2) * 512]; PIN4(w##bb##_2) \
    w##bb##_3 = wsrc[(b_ * 4 + 3) * 512]; PIN4(w##bb##_3) }

#define DOTB(bb, tv) \
    D2Q(acc0, w##bb##_0, tv) D2Q(acc1, w##bb##_1, tv) \
    D2Q(acc2, w##bb##_2, tv) D2Q(acc3, w##bb##_3, tv)

// R20 champion (1865us) VERBATIM in structure -- register-resident W,
// same-XCD quads via XCC_ID rank, phase A before relaxed tid0 poll, fp32
// outH exchange (fresh addresses, plain store/load), DPP reduce, signal
// hoist, top-of-step X prefetch (full-step completion window -- R21 proved
// moving it post-signal shrinks the window below HBM latency and stalls
// the tail). ONE change: per-step 64-bit address chains replaced with
// PERSISTENT POINTERS advanced by RN each step (srcB starts at tanh0 and
// switches to the outH stream after t=0) -- cuts per-step addressing VALU.
__global__ void __launch_bounds__(512, 1) rnn_step_kernel(
    const float* __restrict__ h0,
    const float* __restrict__ X,
    const uint4* __restrict__ Wpk,     // [4 part][4 band][4 i][512 tid]
    const float* __restrict__ tanh0,
    float* __restrict__ outH,
    unsigned* __restrict__ ctr,
    unsigned* __restrict__ xcdctr)
{
    extern __shared__ unsigned char smem[];
    unsigned* ownpk = (unsigned*)smem;               // 64 u32: own th pairs
    int*      bc    = (int*)(smem + 256);
    unsigned* lctr  = (unsigned*)(smem + 264);

    const int tid = threadIdx.x;
    if (tid == 0) {
        unsigned xcd;
        asm volatile("s_getreg_b32 %0, hwreg(HW_REG_XCC_ID)" : "=s"(xcd));
        xcd &= 7u;
        unsigned rank = __hip_atomic_fetch_add(&xcdctr[xcd], 1u,
                            __ATOMIC_RELAXED, __HIP_MEMORY_SCOPE_AGENT) & 31u;
        int slot = (int)(xcd * 32u + rank);   // 0..255
        bc[0] = slot >> 2;                    // batch 0..63
        bc[1] = slot & 3;                     // part  0..3
        *lctr = 0u;
    }
    __syncthreads();
    const int batch = bc[0], part = bc[1];

    // W fragment -> 16 named uint4 registers (rotated: w0_* = own band)
    uint4 w0_0, w0_1, w0_2, w0_3;
    uint4 w1_0, w1_1, w1_2, w1_3;
    uint4 w2_0, w2_1, w2_2, w2_3;
    uint4 w3_0, w3_1, w3_2, w3_3;
    {
        const uint4* wsrc = Wpk + part * 8192 + tid;
        LOADB(0) LOADB(1) LOADB(2) LOADB(3)
    }

    const int rg = tid >> 4;                  // 0..31 : 4-row group
    const int kc = tid & 15;                  // 0..15 : 8-k sub-chunk per band
    const int row0 = part * 128 + rg * 4;

    // persistent pointers (advanced by RN per step; no per-step mul chains)
    const float* srcB  = tanh0;                                   // phase-B base (t-1 row)
    const float* xPtr  = X    + (size_t)batch * RT * RN + row0;   // X[t] (kc==0 lanes)
    float*       oPtr  = outH + (size_t)batch * RT * RN + row0;   // outH[t] (kc==0 lanes)
    const float* oBase = outH + (size_t)batch * RT * RN;          // srcB after t=0

    float4 h = {0, 0, 0, 0};
    float4 xv = {0, 0, 0, 0};
    if (kc == 0) {
        h = *reinterpret_cast<const float4*>(h0 + row0);
        float t0 = tanhf(h.x), t1 = tanhf(h.y), t2 = tanhf(h.z), t3 = tanhf(h.w);
        ownpk[2 * rg]     = pack2(t0, t1);
        ownpk[2 * rg + 1] = pack2(t2, t3);
        xv = *reinterpret_cast<const float4*>(xPtr);   // x_0
    }

    unsigned* gctr = ctr + batch * 32;        // 128B line per quad
    __syncthreads();                          // ownpk staged

    #pragma unroll 1
    for (int t = 0; t < RT; ++t) {
        // 2-deep X prefetch: issue X[t+1] now; full-step window to complete
        float4 xn = {0, 0, 0, 0};
        if (kc == 0) {
            const float* xnp = (t + 1 < RT) ? (xPtr + RN) : xPtr;
            xn = *reinterpret_cast<const float4*>(xnp);
        }

        // ---- phase A: own band from registers + ownpk (no partner dep) ----
        float acc0 = 0.f, acc1 = 0.f, acc2 = 0.f, acc3 = 0.f;
        {
            uint4 th = *reinterpret_cast<const uint4*>(&ownpk[4 * kc]);
            DOTB(0, th)
        }

        // ---- wait for all 4 parts of step t-1 (tid0 poll + barrier bcast) ----
        if (tid == 0 && t > 0) {
            const unsigned tgt = 4u * (unsigned)t;
            while (__hip_atomic_load(gctr, __ATOMIC_RELAXED,
                                     __HIP_MEMORY_SCOPE_AGENT) < tgt)
                __builtin_amdgcn_s_sleep(1);
        }
        __syncthreads();

        // ---- phase B: 3 partner bands, fp32 srcB -> pkrtz -> register dots ----
        {
            const int b1 = (part + 1) & 3;
            const float* p = srcB + b1 * 128 + kc * 8;
            float4 f0 = *reinterpret_cast<const float4*>(p);
            float4 f1 = *reinterpret_cast<const float4*>(p + 4);
            uint4 tv = make_uint4(pkrtz(f0.x, f0.y), pkrtz(f0.z, f0.w),
                                  pkrtz(f1.x, f1.y), pkrtz(f1.z, f1.w));
            DOTB(1, tv)
        }
        {
            const int b2 = (part + 2) & 3;
            const float* p = srcB + b2 * 128 + kc * 8;
            float4 f0 = *reinterpret_cast<const float4*>(p);
            float4 f1 = *reinterpret_cast<const float4*>(p + 4);
            uint4 tv = make_uint4(pkrtz(f0.x, f0.y), pkrtz(f0.z, f0.w),
                                  pkrtz(f1.x, f1.y), pkrtz(f1.z, f1.w));
            DOTB(2, tv)
        }
        {
            const int b3 = (part + 3) & 3;
            const float* p = srcB + b3 * 128 + kc * 8;
            float4 f0 = *reinterpret_cast<const float4*>(p);
            float4 f1 = *reinterpret_cast<const float4*>(p + 4);
            uint4 tv = make_uint4(pkrtz(f0.x, f0.y), pkrtz(f0.z, f0.w),
                                  pkrtz(f1.x, f1.y), pkrtz(f1.z, f1.w));
            DOTB(3, tv)
        }

        // ---- 16-lane all-reduce in VALU (DPP) ----
        acc0 = red16(acc0); acc1 = red16(acc1);
        acc2 = red16(acc2); acc3 = red16(acc3);

        if (kc == 0) {
            h.x = 0.9f * h.x + 0.1f * (acc0 + xv.x);
            h.y = 0.9f * h.y + 0.1f * (acc1 + xv.y);
            h.z = 0.9f * h.z + 0.1f * (acc2 + xv.z);
            h.w = 0.9f * h.w + 0.1f * (acc3 + xv.w);
            float t0 = fast_tanh(h.x), t1 = fast_tanh(h.y);
            float t2 = fast_tanh(h.z), t3 = fast_tanh(h.w);
            *reinterpret_cast<float4*>(oPtr) = make_float4(t0, t1, t2, t3);
            ownpk[2 * rg]     = pack2(t0, t1);
            ownpk[2 * rg + 1] = pack2(t2, t3);
        }

        // ---- signal hoist: per-wave drain -> LDS arrival -> 8th wave fires ----
        asm volatile("s_waitcnt vmcnt(0)" ::: "memory");   // stores in XCD L2
        if ((tid & 63) == 0) {
            unsigned a = __hip_atomic_fetch_add(lctr, 1u, __ATOMIC_RELAXED,
                                                __HIP_MEMORY_SCOPE_WORKGROUP);
            if ((a & 7u) == 7u)
                __hip_atomic_fetch_add(gctr, 1u, __ATOMIC_RELAXED,
                                       __HIP_MEMORY_SCOPE_AGENT);
        }
        __syncthreads();   // ownpk coherence for next step's phase A
        xv = xn;

        // advance persistent pointers (srcB: tanh0 -> outH stream after t=0)
        srcB = (t == 0) ? oBase : (srcB + RN);
        xPtr += RN;
        oPtr += RN;
    }
}

// one-time: W -> f16 pairs in exact per-read order
// Wpk[part*8192 + (b*4+i)*512 + tid] = W[part*128+(tid>>4)*4+i][b*128+(tid&15)*8 ..+8]
__global__ void pack_w(const float* __restrict__ W, uint4* __restrict__ Wpk)
{
    int o = blockIdx.x * blockDim.x + threadIdx.x;
    if (o >= 32768) return;
    int part = o >> 13;
    int b    = (o >> 11) & 3;
    int i    = (o >> 9) & 3;
    int tid  = o & 511;
    int row  = part * 128 + (tid >> 4) * 4 + i;
    int k0   = b * 128 + (tid & 15) * 8;
    const float* s = W + (size_t)row * RN + k0;
    uint4 v;
    v.x = pack2(s[0], s[1]); v.y = pack2(s[2], s[3]);
    v.z = pack2(s[4], s[5]); v.w = pack2(s[6], s[7]);
    Wpk[o] = v;
}

// geometry epilogue: geo[b,t,:] = hidden[b,t,:] @ Gw^T + Gb ; one wave per (b,t)
__global__ void geom_kernel(const float* __restrict__ hid,
                            const float* __restrict__ Gw,
                            const float* __restrict__ Gb,
                            float* __restrict__ geo)
{
    const int wid  = (blockIdx.x * blockDim.x + threadIdx.x) >> 6;
    const int lane = threadIdx.x & 63;
    if (wid >= RB * RT) return;
    const float* rowp = hid + (size_t)wid * RN;
    float g0 = 0.f, g1 = 0.f;
    #pragma unroll
    for (int j = 0; j < 8; ++j) {
        float v = rowp[lane + 64 * j];
        g0 = fmaf(v, Gw[lane + 64 * j], g0);
        g1 = fmaf(v, Gw[RN + lane + 64 * j], g1);
    }
    #pragma unroll
    for (int m = 32; m >= 1; m >>= 1) {
        g0 += __shfl_xor(g0, m);
        g1 += __shfl_xor(g1, m);
    }
    if (lane == 0) {
        geo[(size_t)wid * 2]     = g0 + Gb[0];
        geo[(size_t)wid * 2 + 1] = g1 + Gb[1];
    }
}

// per-launch init: tanh(h0) table + zero counters (ws poisoned once, never
// re-poisoned -> re-init every call; deterministic)
__global__ void init_misc(const float* __restrict__ h0,
                          float* __restrict__ tanh0,
                          unsigned* __restrict__ ctr,
                          unsigned* __restrict__ xcdctr)
{
    int i = blockIdx.x * blockDim.x + threadIdx.x;
    if (i < RN) tanh0[i] = tanhf(h0[i]);
    if (i < RB * 32) ctr[i] = 0u;
    if (i < 8) xcdctr[i] = 0u;
}

extern "C" void kernel_launch(void* const* d_in, const int* in_sizes, int n_in,
                              void* d_out, int out_size, void* d_ws, size_t ws_size,
                              hipStream_t stream)
{
    const float* h0 = (const float*)d_in[0];
    const float* X  = (const float*)d_in[1];
    const float* W  = (const float*)d_in[2];
    const float* Gw = (const float*)d_in[3];
    const float* Gb = (const float*)d_in[4];

    float* outH = (float*)d_out;
    float* geo  = outH + (size_t)RB * RT * RN;

    float*    tanh0  = (float*)d_ws;                  // 512 f32
    unsigned* ctr    = (unsigned*)d_ws + RN;          // 64*32 u32
    unsigned* xcdctr = ctr + RB * 32;                 // 8 u32
    uint4*    Wpk    = (uint4*)(((uintptr_t)(xcdctr + 8) + 63) & ~(uintptr_t)63);

    (void)hipFuncSetAttribute((const void*)rnn_step_kernel,
                              hipFuncAttributeMaxDynamicSharedMemorySize, SMEM_BYTES);

    pack_w<<<64, 512, 0, stream>>>(W, Wpk);
    init_misc<<<8, 512, 0, stream>>>(h0, tanh0, ctr, xcdctr);

    void* kargs[] = { (void*)&h0, (void*)&X, (void*)&Wpk, (void*)&tanh0,
                      (void*)&outH, (void*)&ctr, (void*)&xcdctr };
    (void)hipLaunchCooperativeKernel(rnn_step_kernel, dim3(256), dim3(512),
                                     kargs, SMEM_BYTES, stream);

    geom_kernel<<<(RB * RT * 64 + 255) / 256, 256, 0, stream>>>(outH, Gw, Gb, geo);
}